// Round 2
// baseline (344.677 us; speedup 1.0000x reference)
//
#include <hip/hip_runtime.h>
#include <stdint.h>

#define NQ 14
#define DIM 16384
#define HALF_DIM 8192
#define NL 6
#define NBATCH 1024
#define PI_F 3.14159265358979323846f
#define BLOCK 512

struct GateMasks {
    uint16_t m[NL][NQ];   // pair XOR mask for layer l, qubit q (l>=1)
    uint16_t g[NL][NQ];   // parity mask selecting the "bit=0" side
    uint16_t gout[2];     // parity masks for final Z expectations (qubits 0,1)
    uint16_t pad;
};

// ---------------- normalization prepass: per-feature min / scale ----------------
__global__ __launch_bounds__(256) void qs_norm_kernel(const float* __restrict__ x,
                                                      float* __restrict__ nrm)
{
    const int q = blockIdx.x;
    const int tid = threadIdx.x;
    float mn = 3.0e38f, mx = -3.0e38f;
    for (int r = tid; r < NBATCH; r += 256) {
        const float v = x[r * NQ + q];
        mn = fminf(mn, v);
        mx = fmaxf(mx, v);
    }
#pragma unroll
    for (int off = 32; off > 0; off >>= 1) {
        mn = fminf(mn, __shfl_down(mn, off));
        mx = fmaxf(mx, __shfl_down(mx, off));
    }
    __shared__ float smn[4], smx[4];
    const int wid = tid >> 6, lane = tid & 63;
    if (lane == 0) { smn[wid] = mn; smx[wid] = mx; }
    __syncthreads();
    if (tid == 0) {
        mn = fminf(fminf(smn[0], smn[1]), fminf(smn[2], smn[3]));
        mx = fmaxf(fmaxf(smx[0], smx[1]), fmaxf(smx[2], smx[3]));
        nrm[q] = mn;
        nrm[NQ + q] = PI_F / (mx - mn + 1e-8f);
    }
}

// ---------------- main: one block per batch element, state in LDS ----------------
__global__ __launch_bounds__(BLOCK) void qs_main_kernel(const float* __restrict__ x,
                                                        const float* __restrict__ w,
                                                        const float* __restrict__ nrm,
                                                        float* __restrict__ out,
                                                        const GateMasks gm)
{
    __shared__ float st[DIM];
    __shared__ float red0[BLOCK / 64], red1[BLOCK / 64];
    const int b = blockIdx.x;
    const int tid = threadIdx.x;

    // merged encoding + layer-0 angles -> product state coefficients
    float ci[NQ], si[NQ];
#pragma unroll
    for (int q = 0; q < NQ; ++q) {
        const float ang = (x[b * NQ + q] - nrm[q]) * nrm[NQ + q] + w[q];
        const float h = 0.5f * ang;
        ci[q] = cosf(h);
        si[q] = sinf(h);
    }
    // product-state init: amplitude(i) = prod_q (bit_{13-q}(i) ? sin : cos)
    for (int i = tid; i < DIM; i += BLOCK) {
        float v = 1.0f;
#pragma unroll
        for (int q = 0; q < NQ; ++q)
            v *= ((i >> (NQ - 1 - q)) & 1) ? si[q] : ci[q];
        st[i] = v;
    }

    // layers 1..5: generalized RY passes (CNOT chains folded into masks)
    for (int l = 1; l < NL; ++l) {
#pragma unroll 1
        for (int q = 0; q < NQ; ++q) {
            __syncthreads();
            const float h = 0.5f * w[l * NQ + q];
            const float c = cosf(h), s = sinf(h);
            const unsigned m = gm.m[l][q];
            const unsigned g = gm.g[l][q];
            const unsigned lb = m & (0u - m);   // lowest set bit
            const unsigned lo = lb - 1u;
#pragma unroll 4
            for (int t = tid; t < HALF_DIM; t += BLOCK) {
                const unsigned tt = (unsigned)t;
                const unsigned i0 = ((tt & ~lo) << 1) | (tt & lo);
                const unsigned i1 = i0 ^ m;
                const float u = st[i0];
                const float v = st[i1];
                // exactly one of (i0,i1) has parity(i&g)==0 -> that one is the "bit=0" side
                const float ss = (__popc(i0 & g) & 1) ? -s : s;
                st[i0] = fmaf(c, u, -ss * v);
                st[i1] = fmaf(c, v, ss * u);
            }
        }
    }
    __syncthreads();

    // expectations <Z_0>, <Z_1> with sign = parity of masked bits (final chain folded in)
    float e0 = 0.0f, e1 = 0.0f;
    const unsigned g0 = gm.gout[0], g1 = gm.gout[1];
    for (int i = tid; i < DIM; i += BLOCK) {
        const float a = st[i];
        const float p = a * a;
        e0 += (__popc(i & g0) & 1) ? -p : p;
        e1 += (__popc(i & g1) & 1) ? -p : p;
    }
#pragma unroll
    for (int off = 32; off > 0; off >>= 1) {
        e0 += __shfl_down(e0, off);
        e1 += __shfl_down(e1, off);
    }
    const int wid = tid >> 6, lane = tid & 63;
    if (lane == 0) { red0[wid] = e0; red1[wid] = e1; }
    __syncthreads();
    if (tid == 0) {
        float a0 = 0.0f, a1 = 0.0f;
#pragma unroll
        for (int i = 0; i < BLOCK / 64; ++i) { a0 += red0[i]; a1 += red1[i]; }
        out[b * 2 + 0] = a0;
        out[b * 2 + 1] = a1;
    }
}

// ---------------- host-side GF(2) bit-matrix algebra for the masks ----------------
static void bitmat_mul(const uint16_t* A, const uint16_t* B, uint16_t* C) {
    // C = A o B  (apply B, then A): rowC[p] = XOR_{j in rowA[p]} rowB[j]
    for (int p = 0; p < NQ; ++p) {
        uint16_t r = 0;
        for (int j = 0; j < NQ; ++j)
            if ((A[p] >> j) & 1) r ^= B[j];
        C[p] = r;
    }
}

extern "C" void kernel_launch(void* const* d_in, const int* in_sizes, int n_in,
                              void* d_out, int out_size, void* d_ws, size_t ws_size,
                              hipStream_t stream)
{
    const float* x = (const float*)d_in[0];   // (1024, 14) f32
    const float* w = (const float*)d_in[1];   // (6, 14) f32
    float* out = (float*)d_out;               // (1024, 2) f32
    float* nrm = (float*)d_ws;                // 28 floats scratch

    // Chain permutation: y = U x, U = suffix-xor (row p = bits p..13).
    // After l chains our array index i holds ref amplitude at A*i, A = U^l.
    // RY on qubit q (bit p=13-q): partner mask m = column p of A^{-1} = (I+S)^l,
    // "bit=0" side has parity(i & row_p(A)) == 0.
    GateMasks gm = {};
    uint16_t U[NQ], IS[NQ], A[NQ], Inv[NQ], T[NQ];
    const uint16_t FULL = (uint16_t)((1u << NQ) - 1u);
    for (int p = 0; p < NQ; ++p) {
        U[p]  = (uint16_t)(FULL & ~((1u << p) - 1u));
        IS[p] = (uint16_t)((1u << p) | ((p + 1 < NQ) ? (1u << (p + 1)) : 0u));
        A[p]  = (uint16_t)(1u << p);
        Inv[p] = (uint16_t)(1u << p);
    }
    for (int l = 1; l < NL; ++l) {
        bitmat_mul(U, A, T);   for (int p = 0; p < NQ; ++p) A[p] = T[p];
        bitmat_mul(Inv, IS, T); for (int p = 0; p < NQ; ++p) Inv[p] = T[p];
        for (int q = 0; q < NQ; ++q) {
            const int p = NQ - 1 - q;
            uint16_t mm = 0;
            for (int j = 0; j < NQ; ++j) mm |= (uint16_t)(((Inv[j] >> p) & 1u) << j);
            gm.m[l][q] = mm;
            gm.g[l][q] = A[p];
        }
    }
    bitmat_mul(U, A, T);        // A_6 = U^6 for the final expectation masks
    gm.gout[0] = T[NQ - 1];     // qubit 0 -> bit 13
    gm.gout[1] = T[NQ - 2];     // qubit 1 -> bit 12

    qs_norm_kernel<<<NQ, 256, 0, stream>>>(x, nrm);
    qs_main_kernel<<<NBATCH, BLOCK, 0, stream>>>(x, w, nrm, out, gm);
}